// Round 8
// baseline (709.431 us; speedup 1.0000x reference)
//
#include <hip/hip_runtime.h>

#define DT 0.1f
#define NSTEPS 10

#if __has_builtin(__builtin_amdgcn_exp2f)
#define EXP2(x) __builtin_amdgcn_exp2f(x)
#else
#define EXP2(x) exp2f(x)
#endif

#if __has_builtin(__builtin_amdgcn_rcpf)
#define RCP(x) __builtin_amdgcn_rcpf(x)
#else
#define RCP(x) (1.0f / (x))
#endif

#if __has_builtin(__builtin_amdgcn_sqrtf)
#define SQRTF(x) __builtin_amdgcn_sqrtf(x)
#else
#define SQRTF(x) sqrtf(x)
#endif

// tanh(x) = 1 - 2/(e^{2x}+1), e^{2x} = exp2(2*log2e*x).
// NaN-free without clamping: x->+inf: exp2->inf, rcp(inf)=0 -> 1;
// x->-inf: exp2->0, rcp(1)=1 -> -1. 5 instructions, 2 trans.
static __device__ __forceinline__ float tanh1(float x) {
    float e = EXP2(x * 2.8853900818f);
    float r = RCP(e + 1.0f);
    return fmaf(r, -2.0f, 1.0f);
}

// tanh-MLP on 4 rows with layer-1 pre-folded: z1 = M*s + c (M uniform, c per-row).
static __device__ __forceinline__ void policy4(
    const float M[8][2], const float c[8][4],
    const float* __restrict__ w2, const float* __restrict__ b2,
    const float* __restrict__ w3, const float* __restrict__ b3,
    const float sx[4], const float sy[4],
    float o0[4], float o1[4])
{
    float h[4][8];
#pragma unroll
    for (int j = 0; j < 8; ++j) {
        float m0 = M[j][0], m1 = M[j][1];
#pragma unroll
        for (int r = 0; r < 4; ++r)
            h[r][j] = tanh1(fmaf(m0, sx[r], fmaf(m1, sy[r], c[j][r])));
    }

    float g[4][8];
#pragma unroll
    for (int j = 0; j < 8; ++j) {
        float wk0 = w2[j * 8 + 0];
        float wk1 = w2[j * 8 + 1];
        float wk2 = w2[j * 8 + 2];
        float wk3 = w2[j * 8 + 3];
        float wk4 = w2[j * 8 + 4];
        float wk5 = w2[j * 8 + 5];
        float wk6 = w2[j * 8 + 6];
        float wk7 = w2[j * 8 + 7];
        float bj  = b2[j];
#pragma unroll
        for (int r = 0; r < 4; ++r) {
            float z = wk0 * h[r][0];
            z = fmaf(wk1, h[r][1], z);
            z = fmaf(wk2, h[r][2], z);
            z = fmaf(wk3, h[r][3], z);
            z = fmaf(wk4, h[r][4], z);
            z = fmaf(wk5, h[r][5], z);
            z = fmaf(wk6, h[r][6], z);
            z = fmaf(wk7, h[r][7], z);
            g[r][j] = tanh1(z + bj);
        }
    }

    {
        float u0 = w3[0], u1 = w3[1], u2 = w3[2], u3 = w3[3];
        float u4 = w3[4], u5 = w3[5], u6 = w3[6], u7 = w3[7];
        float v0 = w3[8], v1 = w3[9], v2 = w3[10], v3 = w3[11];
        float v4 = w3[12], v5 = w3[13], v6 = w3[14], v7 = w3[15];
        float e0 = b3[0], e1 = b3[1];
#pragma unroll
        for (int r = 0; r < 4; ++r) {
            float z = u0 * g[r][0];
            z = fmaf(u1, g[r][1], z);
            z = fmaf(u2, g[r][2], z);
            z = fmaf(u3, g[r][3], z);
            z = fmaf(u4, g[r][4], z);
            z = fmaf(u5, g[r][5], z);
            z = fmaf(u6, g[r][6], z);
            z = fmaf(u7, g[r][7], z);
            o0[r] = z + e0;
            float y = v0 * g[r][0];
            y = fmaf(v1, g[r][1], y);
            y = fmaf(v2, g[r][2], y);
            y = fmaf(v3, g[r][3], y);
            y = fmaf(v4, g[r][4], y);
            y = fmaf(v5, g[r][5], y);
            y = fmaf(v6, g[r][6], y);
            y = fmaf(v7, g[r][7], y);
            o1[r] = y + e1;
        }
    }
}

__global__ void __launch_bounds__(256) rollout_kernel(
    const float* __restrict__ s_star, const float* __restrict__ s0,
    const float* __restrict__ fc1_w, const float* __restrict__ fc1_b,
    const float* __restrict__ fc2_w, const float* __restrict__ fc2_b,
    const float* __restrict__ rc1_w, const float* __restrict__ rc1_b,
    const float* __restrict__ rc2_w, const float* __restrict__ rc2_b,
    const float* __restrict__ rc3_w, const float* __restrict__ rc3_b,
    const float* __restrict__ rr1_w, const float* __restrict__ rr1_b,
    const float* __restrict__ rr2_w, const float* __restrict__ rr2_b,
    const float* __restrict__ rr3_w, const float* __restrict__ rr3_b,
    float* __restrict__ out, int NQ)  // NQ = number of row-quads
{
    int i = blockIdx.x * blockDim.x + threadIdx.x;
    if (i >= NQ) return;

    // rows 4i..4i+3
    float4 ssA = reinterpret_cast<const float4*>(s_star)[2 * i];
    float4 ssB = reinterpret_cast<const float4*>(s_star)[2 * i + 1];
    float4 svA = reinterpret_cast<const float4*>(s0)[2 * i];
    float4 svB = reinterpret_cast<const float4*>(s0)[2 * i + 1];

    float ssx[4] = {ssA.x, ssA.z, ssB.x, ssB.z};
    float ssy[4] = {ssA.y, ssA.w, ssB.y, ssB.w};
    float sx[4]  = {svA.x, svA.z, svB.x, svB.z};
    float sy[4]  = {svA.y, svA.w, svB.y, svB.w};

    // Fused linear predictor: ah = A @ s + (A2 @ s_star + cb)  (A uniform)
    float A[2][4];
    float cb[2];
#pragma unroll
    for (int r = 0; r < 2; ++r) {
#pragma unroll
        for (int c = 0; c < 4; ++c) {
            float a = 0.0f;
#pragma unroll
            for (int j = 0; j < 4; ++j)
                a = fmaf(fc2_w[r * 4 + j], fc1_w[j * 4 + c], a);
            A[r][c] = a;
        }
        float b = fc2_b[r];
#pragma unroll
        for (int j = 0; j < 4; ++j) b = fmaf(fc2_w[r * 4 + j], fc1_b[j], b);
        cb[r] = b;
    }

    float d0[4], d1[4], ahs0[4], err[4];
#pragma unroll
    for (int r = 0; r < 4; ++r) {
        d0[r] = fmaf(A[0][2], ssx[r], fmaf(A[0][3], ssy[r], cb[0]));
        d1[r] = fmaf(A[1][2], ssx[r], fmaf(A[1][3], ssy[r], cb[1]));
        ahs0[r] = (ssx[r] > 0.5f) ? -1.0f : 1.0f;
        err[r] = 0.0f;
    }

    // Fold layer-1 of both policies through the affine predictor:
    //   z1_j = (w1[j,0] + w1[j,2]A00 + w1[j,3]A10) sx
    //        + (w1[j,1] + w1[j,2]A01 + w1[j,3]A11) sy
    //        + (w1[j,2] d0 + w1[j,3] d1 + b1[j])
    // M uniform, c per-row and step-invariant.
    float Mrr[8][2], crr[8][4], Mrc[8][2], crc[8][4];
#pragma unroll
    for (int j = 0; j < 8; ++j) {
        float a0 = rr1_w[j * 4 + 0], a1 = rr1_w[j * 4 + 1];
        float a2 = rr1_w[j * 4 + 2], a3 = rr1_w[j * 4 + 3];
        float bj = rr1_b[j];
        Mrr[j][0] = fmaf(a2, A[0][0], fmaf(a3, A[1][0], a0));
        Mrr[j][1] = fmaf(a2, A[0][1], fmaf(a3, A[1][1], a1));
#pragma unroll
        for (int r = 0; r < 4; ++r)
            crr[j][r] = fmaf(a2, d0[r], fmaf(a3, d1[r], bj));
    }
#pragma unroll
    for (int j = 0; j < 8; ++j) {
        float a0 = rc1_w[j * 4 + 0], a1 = rc1_w[j * 4 + 1];
        float a2 = rc1_w[j * 4 + 2], a3 = rc1_w[j * 4 + 3];
        float bj = rc1_b[j];
        Mrc[j][0] = fmaf(a2, A[0][0], fmaf(a3, A[1][0], a0));
        Mrc[j][1] = fmaf(a2, A[0][1], fmaf(a3, A[1][1], a1));
#pragma unroll
        for (int r = 0; r < 4; ++r)
            crc[j][r] = fmaf(a2, d0[r], fmaf(a3, d1[r], bj));
    }

#pragma unroll 1
    for (int t = 0; t < NSTEPS; ++t) {
        float ah0[4], ah1[4], arr0[4], arr1[4], ar0[4], ar1[4];
#pragma unroll
        for (int r = 0; r < 4; ++r) {
            ah0[r] = fmaf(A[0][0], sx[r], fmaf(A[0][1], sy[r], d0[r]));
            ah1[r] = fmaf(A[1][0], sx[r], fmaf(A[1][1], sy[r], d1[r]));
        }
        policy4(Mrr, crr, rr2_w, rr2_b, rr3_w, rr3_b, sx, sy, arr0, arr1);
        policy4(Mrc, crc, rc2_w, rc2_b, rc3_w, rc3_b, sx, sy, ar0, ar1);

#pragma unroll
        for (int r = 0; r < 4; ++r) {
            sx[r] = fmaf(DT, ar0[r], sx[r]);
            sy[r] = fmaf(DT, ar1[r], sy[r]);

            float dx = ssx[r] - sx[r], dy = ssy[r] - sy[r];
            float n1 = fmaf(dx, dx, dy * dy);
            float ux = arr0[r] - ar0[r], uy = arr1[r] - ar1[r];
            float n2 = fmaf(ux, ux, uy * uy);
            float vx = ahs0[r] - ah0[r];
            float n3 = fmaf(vx, vx, ah1[r] * ah1[r]);

            err[r] = err[r] + SQRTF(n1);
            err[r] = fmaf(0.1f, SQRTF(n2), err[r]);
            err[r] = err[r] + SQRTF(n3);
        }
    }

    float4 o;
    o.x = err[0]; o.y = err[1]; o.z = err[2]; o.w = err[3];
    reinterpret_cast<float4*>(out)[i] = o;
}

extern "C" void kernel_launch(void* const* d_in, const int* in_sizes, int n_in,
                              void* d_out, int out_size, void* d_ws, size_t ws_size,
                              hipStream_t stream) {
    const float* s_star = (const float*)d_in[0];
    const float* s0     = (const float*)d_in[1];
    const float* fc1_w  = (const float*)d_in[2];
    const float* fc1_b  = (const float*)d_in[3];
    const float* fc2_w  = (const float*)d_in[4];
    const float* fc2_b  = (const float*)d_in[5];
    const float* rc1_w  = (const float*)d_in[6];
    const float* rc1_b  = (const float*)d_in[7];
    const float* rc2_w  = (const float*)d_in[8];
    const float* rc2_b  = (const float*)d_in[9];
    const float* rc3_w  = (const float*)d_in[10];
    const float* rc3_b  = (const float*)d_in[11];
    const float* rr1_w  = (const float*)d_in[12];
    const float* rr1_b  = (const float*)d_in[13];
    const float* rr2_w  = (const float*)d_in[14];
    const float* rr2_b  = (const float*)d_in[15];
    const float* rr3_w  = (const float*)d_in[16];
    const float* rr3_b  = (const float*)d_in[17];
    float* out = (float*)d_out;

    int B = in_sizes[0] / 2;   // rows
    int NQ = B / 4;            // row-quads (B = 4194304)
    int block = 256;
    int grid = (NQ + block - 1) / block;
    rollout_kernel<<<grid, block, 0, stream>>>(
        s_star, s0, fc1_w, fc1_b, fc2_w, fc2_b,
        rc1_w, rc1_b, rc2_w, rc2_b, rc3_w, rc3_b,
        rr1_w, rr1_b, rr2_w, rr2_b, rr3_w, rr3_b,
        out, NQ);
}

// Round 9
// 606.634 us; speedup vs baseline: 1.1695x; 1.1695x over previous
//
#include <hip/hip_runtime.h>

#define DT 0.1f
#define NSTEPS 10

#if __has_builtin(__builtin_amdgcn_exp2f)
#define EXP2(x) __builtin_amdgcn_exp2f(x)
#else
#define EXP2(x) exp2f(x)
#endif

#if __has_builtin(__builtin_amdgcn_rcpf)
#define RCP(x) __builtin_amdgcn_rcpf(x)
#else
#define RCP(x) (1.0f / (x))
#endif

#if __has_builtin(__builtin_amdgcn_sqrtf)
#define SQRTF(x) __builtin_amdgcn_sqrtf(x)
#else
#define SQRTF(x) sqrtf(x)
#endif

// tanh(x) = 1 - 2/(e^{2x}+1). NaN-free without clamping:
// x->+inf: rcp(inf)=0 -> 1 ; x->-inf: rcp(1)=1 -> -1. 5 VALU ops.
static __device__ __forceinline__ float tanh1(float x) {
    float e = EXP2(x * 2.8853900818f);
    float r = RCP(e + 1.0f);
    return fmaf(r, -2.0f, 1.0f);
}

// Weight lane-storage: weight idx lives in lane (idx&63) of VGPR (idx>>6).
// WGET(IDX) with compile-time IDX -> one v_readlane_b32 into an SGPR.
#define WGET(IDX) __int_as_float(__builtin_amdgcn_readlane(                         \
    ((IDX) < 64 ? wv0 : (IDX) < 128 ? wv1 : (IDX) < 192 ? wv2 : (IDX) < 256 ? wv3  \
                      : wv4),                                                        \
    (IDX) & 63))

// Packed layout per policy (BASE=0 for rr, BASE=130 for rc):
//   w1: +0 (32) | b1: +32 (8) | w2: +40 (64) | b2: +104 (8) | w3: +112 (16) | b3: +128 (2)
template <int BASE>
static __device__ __forceinline__ void policy4(
    int wv0, int wv1, int wv2, int wv3, int wv4,
    const float c0[4], const float c1[4], const float c2[4], const float c3[4],
    float o0[4], float o1[4])
{
    float h[4][8];
#pragma unroll
    for (int j = 0; j < 8; ++j) {
        float w0 = WGET(BASE + j * 4 + 0);
        float w1 = WGET(BASE + j * 4 + 1);
        float w2 = WGET(BASE + j * 4 + 2);
        float w3 = WGET(BASE + j * 4 + 3);
        float bb = WGET(BASE + 32 + j);
#pragma unroll
        for (int r = 0; r < 4; ++r) {
            float z = w0 * c0[r];
            z = fmaf(w1, c1[r], z);
            z = fmaf(w2, c2[r], z);
            z = fmaf(w3, c3[r], z);
            h[r][j] = tanh1(z + bb);
        }
    }

    float g[4][8];
#pragma unroll
    for (int j = 0; j < 8; ++j) {
        float k0 = WGET(BASE + 40 + j * 8 + 0);
        float k1 = WGET(BASE + 40 + j * 8 + 1);
        float k2 = WGET(BASE + 40 + j * 8 + 2);
        float k3 = WGET(BASE + 40 + j * 8 + 3);
        float k4 = WGET(BASE + 40 + j * 8 + 4);
        float k5 = WGET(BASE + 40 + j * 8 + 5);
        float k6 = WGET(BASE + 40 + j * 8 + 6);
        float k7 = WGET(BASE + 40 + j * 8 + 7);
        float bb = WGET(BASE + 104 + j);
#pragma unroll
        for (int r = 0; r < 4; ++r) {
            float z = k0 * h[r][0];
            z = fmaf(k1, h[r][1], z);
            z = fmaf(k2, h[r][2], z);
            z = fmaf(k3, h[r][3], z);
            z = fmaf(k4, h[r][4], z);
            z = fmaf(k5, h[r][5], z);
            z = fmaf(k6, h[r][6], z);
            z = fmaf(k7, h[r][7], z);
            g[r][j] = tanh1(z + bb);
        }
    }

    {
        float u0 = WGET(BASE + 112 + 0), u1 = WGET(BASE + 112 + 1);
        float u2 = WGET(BASE + 112 + 2), u3 = WGET(BASE + 112 + 3);
        float u4 = WGET(BASE + 112 + 4), u5 = WGET(BASE + 112 + 5);
        float u6 = WGET(BASE + 112 + 6), u7 = WGET(BASE + 112 + 7);
        float v0 = WGET(BASE + 112 + 8), v1 = WGET(BASE + 112 + 9);
        float v2 = WGET(BASE + 112 + 10), v3 = WGET(BASE + 112 + 11);
        float v4 = WGET(BASE + 112 + 12), v5 = WGET(BASE + 112 + 13);
        float v6 = WGET(BASE + 112 + 14), v7 = WGET(BASE + 112 + 15);
        float e0 = WGET(BASE + 128), e1 = WGET(BASE + 129);
#pragma unroll
        for (int r = 0; r < 4; ++r) {
            float z = u0 * g[r][0];
            z = fmaf(u1, g[r][1], z);
            z = fmaf(u2, g[r][2], z);
            z = fmaf(u3, g[r][3], z);
            z = fmaf(u4, g[r][4], z);
            z = fmaf(u5, g[r][5], z);
            z = fmaf(u6, g[r][6], z);
            z = fmaf(u7, g[r][7], z);
            o0[r] = z + e0;
            float y = v0 * g[r][0];
            y = fmaf(v1, g[r][1], y);
            y = fmaf(v2, g[r][2], y);
            y = fmaf(v3, g[r][3], y);
            y = fmaf(v4, g[r][4], y);
            y = fmaf(v5, g[r][5], y);
            y = fmaf(v6, g[r][6], y);
            y = fmaf(v7, g[r][7], y);
            o1[r] = y + e1;
        }
    }
}

// One-time gather of packed weight idx (0..259) from the 12 source arrays.
static __device__ float gather_w(int idx,
    const float* __restrict__ rr1_w, const float* __restrict__ rr1_b,
    const float* __restrict__ rr2_w, const float* __restrict__ rr2_b,
    const float* __restrict__ rr3_w, const float* __restrict__ rr3_b,
    const float* __restrict__ rc1_w, const float* __restrict__ rc1_b,
    const float* __restrict__ rc2_w, const float* __restrict__ rc2_b,
    const float* __restrict__ rc3_w, const float* __restrict__ rc3_b)
{
    if (idx < 130) {
        if (idx < 32)  return rr1_w[idx];
        if (idx < 40)  return rr1_b[idx - 32];
        if (idx < 104) return rr2_w[idx - 40];
        if (idx < 112) return rr2_b[idx - 104];
        if (idx < 128) return rr3_w[idx - 112];
        return rr3_b[idx - 128];
    }
    int k = idx - 130;
    if (k < 32)  return rc1_w[k];
    if (k < 40)  return rc1_b[k - 32];
    if (k < 104) return rc2_w[k - 40];
    if (k < 112) return rc2_b[k - 104];
    if (k < 128) return rc3_w[k - 112];
    if (k < 130) return rc3_b[k - 128];
    return 0.0f;
}

__global__ void __launch_bounds__(256) rollout_kernel(
    const float* __restrict__ s_star, const float* __restrict__ s0,
    const float* __restrict__ fc1_w, const float* __restrict__ fc1_b,
    const float* __restrict__ fc2_w, const float* __restrict__ fc2_b,
    const float* __restrict__ rc1_w, const float* __restrict__ rc1_b,
    const float* __restrict__ rc2_w, const float* __restrict__ rc2_b,
    const float* __restrict__ rc3_w, const float* __restrict__ rc3_b,
    const float* __restrict__ rr1_w, const float* __restrict__ rr1_b,
    const float* __restrict__ rr2_w, const float* __restrict__ rr2_b,
    const float* __restrict__ rr3_w, const float* __restrict__ rr3_b,
    float* __restrict__ out, int NQ)  // NQ = number of row-quads
{
    // Lane-resident packed weights: MUST be loaded by every lane before any
    // early return, so readlane never reads an uninitialized lane.
    int lane = threadIdx.x & 63;
    int wv0 = __float_as_int(gather_w(lane,
        rr1_w, rr1_b, rr2_w, rr2_b, rr3_w, rr3_b,
        rc1_w, rc1_b, rc2_w, rc2_b, rc3_w, rc3_b));
    int wv1 = __float_as_int(gather_w(64 + lane,
        rr1_w, rr1_b, rr2_w, rr2_b, rr3_w, rr3_b,
        rc1_w, rc1_b, rc2_w, rc2_b, rc3_w, rc3_b));
    int wv2 = __float_as_int(gather_w(128 + lane,
        rr1_w, rr1_b, rr2_w, rr2_b, rr3_w, rr3_b,
        rc1_w, rc1_b, rc2_w, rc2_b, rc3_w, rc3_b));
    int wv3 = __float_as_int(gather_w(192 + lane,
        rr1_w, rr1_b, rr2_w, rr2_b, rr3_w, rr3_b,
        rc1_w, rc1_b, rc2_w, rc2_b, rc3_w, rc3_b));
    int wv4 = __float_as_int(gather_w(256 + lane,
        rr1_w, rr1_b, rr2_w, rr2_b, rr3_w, rr3_b,
        rc1_w, rc1_b, rc2_w, rc2_b, rc3_w, rc3_b));

    int i = blockIdx.x * blockDim.x + threadIdx.x;
    if (i >= NQ) return;

    // rows 4i..4i+3
    float4 ssA = reinterpret_cast<const float4*>(s_star)[2 * i];
    float4 ssB = reinterpret_cast<const float4*>(s_star)[2 * i + 1];
    float4 svA = reinterpret_cast<const float4*>(s0)[2 * i];
    float4 svB = reinterpret_cast<const float4*>(s0)[2 * i + 1];

    float ssx[4] = {ssA.x, ssA.z, ssB.x, ssB.z};
    float ssy[4] = {ssA.y, ssA.w, ssB.y, ssB.w};
    float sx[4]  = {svA.x, svA.z, svB.x, svB.z};
    float sy[4]  = {svA.y, svA.w, svB.y, svB.w};

    // Fused linear predictor: ah = A @ [s, s_star] + cb (uniform A, cb; one-time)
    float A[2][4];
    float cb[2];
#pragma unroll
    for (int r = 0; r < 2; ++r) {
#pragma unroll
        for (int c = 0; c < 4; ++c) {
            float a = 0.0f;
#pragma unroll
            for (int j = 0; j < 4; ++j)
                a = fmaf(fc2_w[r * 4 + j], fc1_w[j * 4 + c], a);
            A[r][c] = a;
        }
        float b = fc2_b[r];
#pragma unroll
        for (int j = 0; j < 4; ++j) b = fmaf(fc2_w[r * 4 + j], fc1_b[j], b);
        cb[r] = b;
    }

    float d0[4], d1[4], ahs0[4], err[4];
#pragma unroll
    for (int r = 0; r < 4; ++r) {
        d0[r] = fmaf(A[0][2], ssx[r], fmaf(A[0][3], ssy[r], cb[0]));
        d1[r] = fmaf(A[1][2], ssx[r], fmaf(A[1][3], ssy[r], cb[1]));
        ahs0[r] = (ssx[r] > 0.5f) ? -1.0f : 1.0f;
        err[r] = 0.0f;
    }

#pragma unroll 1
    for (int t = 0; t < NSTEPS; ++t) {
        float ah0[4], ah1[4], arr0[4], arr1[4], ar0[4], ar1[4];
#pragma unroll
        for (int r = 0; r < 4; ++r) {
            ah0[r] = fmaf(A[0][0], sx[r], fmaf(A[0][1], sy[r], d0[r]));
            ah1[r] = fmaf(A[1][0], sx[r], fmaf(A[1][1], sy[r], d1[r]));
        }
        policy4<0>(wv0, wv1, wv2, wv3, wv4, sx, sy, ah0, ah1, arr0, arr1);
        policy4<130>(wv0, wv1, wv2, wv3, wv4, sx, sy, ah0, ah1, ar0, ar1);

#pragma unroll
        for (int r = 0; r < 4; ++r) {
            sx[r] = fmaf(DT, ar0[r], sx[r]);
            sy[r] = fmaf(DT, ar1[r], sy[r]);

            float dx = ssx[r] - sx[r], dy = ssy[r] - sy[r];
            float n1 = fmaf(dx, dx, dy * dy);
            float ux = arr0[r] - ar0[r], uy = arr1[r] - ar1[r];
            float n2 = fmaf(ux, ux, uy * uy);
            float vx = ahs0[r] - ah0[r];
            float n3 = fmaf(vx, vx, ah1[r] * ah1[r]);

            err[r] = err[r] + SQRTF(n1);
            err[r] = fmaf(0.1f, SQRTF(n2), err[r]);
            err[r] = err[r] + SQRTF(n3);
        }
    }

    float4 o;
    o.x = err[0]; o.y = err[1]; o.z = err[2]; o.w = err[3];
    reinterpret_cast<float4*>(out)[i] = o;
}

extern "C" void kernel_launch(void* const* d_in, const int* in_sizes, int n_in,
                              void* d_out, int out_size, void* d_ws, size_t ws_size,
                              hipStream_t stream) {
    const float* s_star = (const float*)d_in[0];
    const float* s0     = (const float*)d_in[1];
    const float* fc1_w  = (const float*)d_in[2];
    const float* fc1_b  = (const float*)d_in[3];
    const float* fc2_w  = (const float*)d_in[4];
    const float* fc2_b  = (const float*)d_in[5];
    const float* rc1_w  = (const float*)d_in[6];
    const float* rc1_b  = (const float*)d_in[7];
    const float* rc2_w  = (const float*)d_in[8];
    const float* rc2_b  = (const float*)d_in[9];
    const float* rc3_w  = (const float*)d_in[10];
    const float* rc3_b  = (const float*)d_in[11];
    const float* rr1_w  = (const float*)d_in[12];
    const float* rr1_b  = (const float*)d_in[13];
    const float* rr2_w  = (const float*)d_in[14];
    const float* rr2_b  = (const float*)d_in[15];
    const float* rr3_w  = (const float*)d_in[16];
    const float* rr3_b  = (const float*)d_in[17];
    float* out = (float*)d_out;

    int B = in_sizes[0] / 2;   // rows
    int NQ = B / 4;            // row-quads (B = 4194304)
    int block = 256;
    int grid = (NQ + block - 1) / block;
    rollout_kernel<<<grid, block, 0, stream>>>(
        s_star, s0, fc1_w, fc1_b, fc2_w, fc2_b,
        rc1_w, rc1_b, rc2_w, rc2_b, rc3_w, rc3_b,
        rr1_w, rr1_b, rr2_w, rr2_b, rr3_w, rr3_b,
        out, NQ);
}

// Round 10
// 478.705 us; speedup vs baseline: 1.4820x; 1.2672x over previous
//
#include <hip/hip_runtime.h>
#include <hip/hip_fp16.h>

#define DT 0.1f
#define NSTEPS 10

#if __has_builtin(__builtin_amdgcn_sqrtf)
#define SQRTF(x) __builtin_amdgcn_sqrtf(x)
#else
#define SQRTF(x) sqrtf(x)
#endif

static __device__ __forceinline__ __half2 bits2h(int v) {
    return __builtin_bit_cast(__half2, v);
}

// Packed-f16 tanh: tanh(x) = 1 - 2/(exp2(k*x)+1), k = 2*log2(e).
// f16 saturation is NaN-free: exp2 overflow -> inf -> rcp -> 0 -> +1;
// underflow -> 0 -> rcp(1) = 1 -> -1.
static __device__ __forceinline__ __half2 tanh2(__half2 z) {
    const __half2 kk   = __float2half2_rn(2.8853900818f);
    const __half2 one  = __float2half2_rn(1.0f);
    const __half2 mtwo = __float2half2_rn(-2.0f);
    __half2 e = h2exp2(__hmul2(z, kk));
    __half2 r = h2rcp(__hadd2(e, one));
    return __hfma2(r, mtwo, one);
}

// Weight lane-storage: weight idx lives (as a DUPLICATED f16 pair) in lane
// (idx&63) of VGPR (idx>>6). One v_readlane -> SGPR, broadcast to both halves
// of every v_pk_* op that consumes it.
#define WGETH(IDX) bits2h(__builtin_amdgcn_readlane(                                \
    ((IDX) < 64 ? wv0 : (IDX) < 128 ? wv1 : (IDX) < 192 ? wv2 : (IDX) < 256 ? wv3  \
                      : wv4),                                                        \
    (IDX) & 63))

// Packed layout per policy (BASE=0 for rr, BASE=130 for rc):
//   w1: +0 (32) | b1: +32 (8) | w2: +40 (64) | b2: +104 (8) | w3: +112 (16) | b3: +128 (2)
// 4 rows = 2 half2 pairs (rows 2p, 2p+1 in low/high halves).
template <int BASE>
static __device__ __forceinline__ void policy4h(
    int wv0, int wv1, int wv2, int wv3, int wv4,
    const __half2 c0[2], const __half2 c1[2], const __half2 c2[2], const __half2 c3[2],
    __half2 o0[2], __half2 o1[2])
{
    __half2 h[2][8];
#pragma unroll
    for (int j = 0; j < 8; ++j) {
        __half2 w0 = WGETH(BASE + j * 4 + 0);
        __half2 w1 = WGETH(BASE + j * 4 + 1);
        __half2 w2 = WGETH(BASE + j * 4 + 2);
        __half2 w3 = WGETH(BASE + j * 4 + 3);
        __half2 bb = WGETH(BASE + 32 + j);
#pragma unroll
        for (int p = 0; p < 2; ++p) {
            __half2 z = __hmul2(w0, c0[p]);
            z = __hfma2(w1, c1[p], z);
            z = __hfma2(w2, c2[p], z);
            z = __hfma2(w3, c3[p], z);
            h[p][j] = tanh2(__hadd2(z, bb));
        }
    }

    __half2 g[2][8];
#pragma unroll
    for (int j = 0; j < 8; ++j) {
        __half2 k0 = WGETH(BASE + 40 + j * 8 + 0);
        __half2 k1 = WGETH(BASE + 40 + j * 8 + 1);
        __half2 k2 = WGETH(BASE + 40 + j * 8 + 2);
        __half2 k3 = WGETH(BASE + 40 + j * 8 + 3);
        __half2 k4 = WGETH(BASE + 40 + j * 8 + 4);
        __half2 k5 = WGETH(BASE + 40 + j * 8 + 5);
        __half2 k6 = WGETH(BASE + 40 + j * 8 + 6);
        __half2 k7 = WGETH(BASE + 40 + j * 8 + 7);
        __half2 bb = WGETH(BASE + 104 + j);
#pragma unroll
        for (int p = 0; p < 2; ++p) {
            __half2 z = __hmul2(k0, h[p][0]);
            z = __hfma2(k1, h[p][1], z);
            z = __hfma2(k2, h[p][2], z);
            z = __hfma2(k3, h[p][3], z);
            z = __hfma2(k4, h[p][4], z);
            z = __hfma2(k5, h[p][5], z);
            z = __hfma2(k6, h[p][6], z);
            z = __hfma2(k7, h[p][7], z);
            g[p][j] = tanh2(__hadd2(z, bb));
        }
    }

    {
        __half2 u0 = WGETH(BASE + 112 + 0), u1 = WGETH(BASE + 112 + 1);
        __half2 u2 = WGETH(BASE + 112 + 2), u3 = WGETH(BASE + 112 + 3);
        __half2 u4 = WGETH(BASE + 112 + 4), u5 = WGETH(BASE + 112 + 5);
        __half2 u6 = WGETH(BASE + 112 + 6), u7 = WGETH(BASE + 112 + 7);
        __half2 v0 = WGETH(BASE + 112 + 8), v1 = WGETH(BASE + 112 + 9);
        __half2 v2 = WGETH(BASE + 112 + 10), v3 = WGETH(BASE + 112 + 11);
        __half2 v4 = WGETH(BASE + 112 + 12), v5 = WGETH(BASE + 112 + 13);
        __half2 v6 = WGETH(BASE + 112 + 14), v7 = WGETH(BASE + 112 + 15);
        __half2 e0 = WGETH(BASE + 128), e1 = WGETH(BASE + 129);
#pragma unroll
        for (int p = 0; p < 2; ++p) {
            __half2 z = __hmul2(u0, g[p][0]);
            z = __hfma2(u1, g[p][1], z);
            z = __hfma2(u2, g[p][2], z);
            z = __hfma2(u3, g[p][3], z);
            z = __hfma2(u4, g[p][4], z);
            z = __hfma2(u5, g[p][5], z);
            z = __hfma2(u6, g[p][6], z);
            z = __hfma2(u7, g[p][7], z);
            o0[p] = __hadd2(z, e0);
            __half2 y = __hmul2(v0, g[p][0]);
            y = __hfma2(v1, g[p][1], y);
            y = __hfma2(v2, g[p][2], y);
            y = __hfma2(v3, g[p][3], y);
            y = __hfma2(v4, g[p][4], y);
            y = __hfma2(v5, g[p][5], y);
            y = __hfma2(v6, g[p][6], y);
            y = __hfma2(v7, g[p][7], y);
            o1[p] = __hadd2(y, e1);
        }
    }
}

// One-time gather of packed weight idx (0..259) from the 12 source arrays.
static __device__ float gather_w(int idx,
    const float* __restrict__ rr1_w, const float* __restrict__ rr1_b,
    const float* __restrict__ rr2_w, const float* __restrict__ rr2_b,
    const float* __restrict__ rr3_w, const float* __restrict__ rr3_b,
    const float* __restrict__ rc1_w, const float* __restrict__ rc1_b,
    const float* __restrict__ rc2_w, const float* __restrict__ rc2_b,
    const float* __restrict__ rc3_w, const float* __restrict__ rc3_b)
{
    if (idx < 130) {
        if (idx < 32)  return rr1_w[idx];
        if (idx < 40)  return rr1_b[idx - 32];
        if (idx < 104) return rr2_w[idx - 40];
        if (idx < 112) return rr2_b[idx - 104];
        if (idx < 128) return rr3_w[idx - 112];
        return rr3_b[idx - 128];
    }
    int k = idx - 130;
    if (k < 32)  return rc1_w[k];
    if (k < 40)  return rc1_b[k - 32];
    if (k < 104) return rc2_w[k - 40];
    if (k < 112) return rc2_b[k - 104];
    if (k < 128) return rc3_w[k - 112];
    if (k < 130) return rc3_b[k - 128];
    return 0.0f;
}

static __device__ __forceinline__ int packh2(float w) {
    __half h = __float2half_rn(w);
    __half2 d = __half2half2(h);
    return __builtin_bit_cast(int, d);
}

__global__ void __launch_bounds__(256) rollout_kernel(
    const float* __restrict__ s_star, const float* __restrict__ s0,
    const float* __restrict__ fc1_w, const float* __restrict__ fc1_b,
    const float* __restrict__ fc2_w, const float* __restrict__ fc2_b,
    const float* __restrict__ rc1_w, const float* __restrict__ rc1_b,
    const float* __restrict__ rc2_w, const float* __restrict__ rc2_b,
    const float* __restrict__ rc3_w, const float* __restrict__ rc3_b,
    const float* __restrict__ rr1_w, const float* __restrict__ rr1_b,
    const float* __restrict__ rr2_w, const float* __restrict__ rr2_b,
    const float* __restrict__ rr3_w, const float* __restrict__ rr3_b,
    float* __restrict__ out, int NQ)  // NQ = number of row-quads
{
    // Lane-resident duplicated-f16 weights: loaded by every lane BEFORE any
    // early return so readlane never sees an uninitialized lane.
    int lane = threadIdx.x & 63;
    int wv0 = packh2(gather_w(lane,
        rr1_w, rr1_b, rr2_w, rr2_b, rr3_w, rr3_b,
        rc1_w, rc1_b, rc2_w, rc2_b, rc3_w, rc3_b));
    int wv1 = packh2(gather_w(64 + lane,
        rr1_w, rr1_b, rr2_w, rr2_b, rr3_w, rr3_b,
        rc1_w, rc1_b, rc2_w, rc2_b, rc3_w, rc3_b));
    int wv2 = packh2(gather_w(128 + lane,
        rr1_w, rr1_b, rr2_w, rr2_b, rr3_w, rr3_b,
        rc1_w, rc1_b, rc2_w, rc2_b, rc3_w, rc3_b));
    int wv3 = packh2(gather_w(192 + lane,
        rr1_w, rr1_b, rr2_w, rr2_b, rr3_w, rr3_b,
        rc1_w, rc1_b, rc2_w, rc2_b, rc3_w, rc3_b));
    int wv4 = packh2(gather_w(256 + lane,
        rr1_w, rr1_b, rr2_w, rr2_b, rr3_w, rr3_b,
        rc1_w, rc1_b, rc2_w, rc2_b, rc3_w, rc3_b));

    int i = blockIdx.x * blockDim.x + threadIdx.x;
    if (i >= NQ) return;

    // rows 4i..4i+3
    float4 ssA = reinterpret_cast<const float4*>(s_star)[2 * i];
    float4 ssB = reinterpret_cast<const float4*>(s_star)[2 * i + 1];
    float4 svA = reinterpret_cast<const float4*>(s0)[2 * i];
    float4 svB = reinterpret_cast<const float4*>(s0)[2 * i + 1];

    float ssx[4] = {ssA.x, ssA.z, ssB.x, ssB.z};
    float ssy[4] = {ssA.y, ssA.w, ssB.y, ssB.w};
    float sx[4]  = {svA.x, svA.z, svB.x, svB.z};
    float sy[4]  = {svA.y, svA.w, svB.y, svB.w};

    // Fused linear predictor: ah = A @ [s, s_star] + cb (uniform A, cb; one-time, f32)
    float A[2][4];
    float cb[2];
#pragma unroll
    for (int r = 0; r < 2; ++r) {
#pragma unroll
        for (int c = 0; c < 4; ++c) {
            float a = 0.0f;
#pragma unroll
            for (int j = 0; j < 4; ++j)
                a = fmaf(fc2_w[r * 4 + j], fc1_w[j * 4 + c], a);
            A[r][c] = a;
        }
        float b = fc2_b[r];
#pragma unroll
        for (int j = 0; j < 4; ++j) b = fmaf(fc2_w[r * 4 + j], fc1_b[j], b);
        cb[r] = b;
    }

    float d0[4], d1[4], ahs0[4], err[4];
#pragma unroll
    for (int r = 0; r < 4; ++r) {
        d0[r] = fmaf(A[0][2], ssx[r], fmaf(A[0][3], ssy[r], cb[0]));
        d1[r] = fmaf(A[1][2], ssx[r], fmaf(A[1][3], ssy[r], cb[1]));
        ahs0[r] = (ssx[r] > 0.5f) ? -1.0f : 1.0f;
        err[r] = 0.0f;
    }

#pragma unroll 1
    for (int t = 0; t < NSTEPS; ++t) {
        float ah0[4], ah1[4];
#pragma unroll
        for (int r = 0; r < 4; ++r) {
            ah0[r] = fmaf(A[0][0], sx[r], fmaf(A[0][1], sy[r], d0[r]));
            ah1[r] = fmaf(A[1][0], sx[r], fmaf(A[1][1], sy[r], d1[r]));
        }

        // pack policy inputs: rows 2p, 2p+1 -> low/high halves
        __half2 c0[2], c1[2], c2[2], c3[2];
#pragma unroll
        for (int p = 0; p < 2; ++p) {
            c0[p] = __floats2half2_rn(sx[2 * p], sx[2 * p + 1]);
            c1[p] = __floats2half2_rn(sy[2 * p], sy[2 * p + 1]);
            c2[p] = __floats2half2_rn(ah0[2 * p], ah0[2 * p + 1]);
            c3[p] = __floats2half2_rn(ah1[2 * p], ah1[2 * p + 1]);
        }

        __half2 arr0h[2], arr1h[2], ar0h[2], ar1h[2];
        policy4h<0>(wv0, wv1, wv2, wv3, wv4, c0, c1, c2, c3, arr0h, arr1h);
        policy4h<130>(wv0, wv1, wv2, wv3, wv4, c0, c1, c2, c3, ar0h, ar1h);

        float arr0[4], arr1[4], ar0[4], ar1[4];
#pragma unroll
        for (int p = 0; p < 2; ++p) {
            arr0[2 * p] = __low2float(arr0h[p]);  arr0[2 * p + 1] = __high2float(arr0h[p]);
            arr1[2 * p] = __low2float(arr1h[p]);  arr1[2 * p + 1] = __high2float(arr1h[p]);
            ar0[2 * p]  = __low2float(ar0h[p]);   ar0[2 * p + 1]  = __high2float(ar0h[p]);
            ar1[2 * p]  = __low2float(ar1h[p]);   ar1[2 * p + 1]  = __high2float(ar1h[p]);
        }

#pragma unroll
        for (int r = 0; r < 4; ++r) {
            sx[r] = fmaf(DT, ar0[r], sx[r]);
            sy[r] = fmaf(DT, ar1[r], sy[r]);

            float dx = ssx[r] - sx[r], dy = ssy[r] - sy[r];
            float n1 = fmaf(dx, dx, dy * dy);
            float ux = arr0[r] - ar0[r], uy = arr1[r] - ar1[r];
            float n2 = fmaf(ux, ux, uy * uy);
            float vx = ahs0[r] - ah0[r];
            float n3 = fmaf(vx, vx, ah1[r] * ah1[r]);

            err[r] = err[r] + SQRTF(n1);
            err[r] = fmaf(0.1f, SQRTF(n2), err[r]);
            err[r] = err[r] + SQRTF(n3);
        }
    }

    float4 o;
    o.x = err[0]; o.y = err[1]; o.z = err[2]; o.w = err[3];
    reinterpret_cast<float4*>(out)[i] = o;
}

extern "C" void kernel_launch(void* const* d_in, const int* in_sizes, int n_in,
                              void* d_out, int out_size, void* d_ws, size_t ws_size,
                              hipStream_t stream) {
    const float* s_star = (const float*)d_in[0];
    const float* s0     = (const float*)d_in[1];
    const float* fc1_w  = (const float*)d_in[2];
    const float* fc1_b  = (const float*)d_in[3];
    const float* fc2_w  = (const float*)d_in[4];
    const float* fc2_b  = (const float*)d_in[5];
    const float* rc1_w  = (const float*)d_in[6];
    const float* rc1_b  = (const float*)d_in[7];
    const float* rc2_w  = (const float*)d_in[8];
    const float* rc2_b  = (const float*)d_in[9];
    const float* rc3_w  = (const float*)d_in[10];
    const float* rc3_b  = (const float*)d_in[11];
    const float* rr1_w  = (const float*)d_in[12];
    const float* rr1_b  = (const float*)d_in[13];
    const float* rr2_w  = (const float*)d_in[14];
    const float* rr2_b  = (const float*)d_in[15];
    const float* rr3_w  = (const float*)d_in[16];
    const float* rr3_b  = (const float*)d_in[17];
    float* out = (float*)d_out;

    int B = in_sizes[0] / 2;   // rows
    int NQ = B / 4;            // row-quads (B = 4194304)
    int block = 256;
    int grid = (NQ + block - 1) / block;
    rollout_kernel<<<grid, block, 0, stream>>>(
        s_star, s0, fc1_w, fc1_b, fc2_w, fc2_b,
        rc1_w, rc1_b, rc2_w, rc2_b, rc3_w, rc3_b,
        rr1_w, rr1_b, rr2_w, rr2_b, rr3_w, rr3_b,
        out, NQ);
}

// Round 11
// 440.528 us; speedup vs baseline: 1.6104x; 1.0867x over previous
//
#include <hip/hip_runtime.h>
#include <hip/hip_fp16.h>

#define DT 0.1f
#define NSTEPS 10

#if __has_builtin(__builtin_amdgcn_sqrtf)
#define SQRTF(x) __builtin_amdgcn_sqrtf(x)
#else
#define SQRTF(x) sqrtf(x)
#endif

static __device__ __forceinline__ __half2 bits2h(int v) {
    return __builtin_bit_cast(__half2, v);
}

// Packed-f16 tanh: tanh(x) = 1 - 2/(exp2(k*x)+1), k = 2*log2(e).
// NaN-free saturation: exp2 overflow->inf->rcp->0->+1 ; underflow->0->rcp(1)=1->-1.
static __device__ __forceinline__ __half2 tanh2(__half2 z) {
    const __half2 kk   = __float2half2_rn(2.8853900818f);
    const __half2 one  = __float2half2_rn(1.0f);
    const __half2 mtwo = __float2half2_rn(-2.0f);
    __half2 e = h2exp2(__hmul2(z, kk));
    __half2 r = h2rcp(__hadd2(e, one));
    return __hfma2(r, mtwo, one);
}

// Weight lane-storage: weight idx lives (as a DUPLICATED f16 pair) in lane
// (idx&63) of VGPR (idx>>6). One v_readlane -> SGPR operand for pk ops.
#define WGETH(IDX) bits2h(__builtin_amdgcn_readlane(                                \
    ((IDX) < 64 ? wv0 : (IDX) < 128 ? wv1 : (IDX) < 192 ? wv2 : (IDX) < 256 ? wv3  \
                      : wv4),                                                        \
    (IDX) & 63))

// Folded layer-1 M coefficients live in wv5: lanes 0..31, idx = MBASE + j*2 + comp.
#define WGETM(IDX) bits2h(__builtin_amdgcn_readlane(wv5, (IDX)))

// Packed layout per policy (BASE=0 for rr, BASE=130 for rc):
//   w1: +0 (32) | b1: +32 (8) | w2: +40 (64) | b2: +104 (8) | w3: +112 (16) | b3: +128 (2)
// Layer-1 is folded: z1 = M*s + c, only w2/b2/w3/b3 are read from wv0..wv4.
// 4 rows = 2 half2 pairs (rows 2p, 2p+1 in low/high halves).
template <int BASE, int MBASE>
static __device__ __forceinline__ void policy4h(
    int wv0, int wv1, int wv2, int wv3, int wv4, int wv5,
    const __half2 ch[8][2],
    const __half2 c0[2], const __half2 c1[2],
    __half2 o0[2], __half2 o1[2])
{
    __half2 h[2][8];
#pragma unroll
    for (int j = 0; j < 8; ++j) {
        __half2 m0 = WGETM(MBASE + j * 2 + 0);
        __half2 m1 = WGETM(MBASE + j * 2 + 1);
#pragma unroll
        for (int p = 0; p < 2; ++p) {
            __half2 z = __hfma2(m0, c0[p], ch[j][p]);
            z = __hfma2(m1, c1[p], z);
            h[p][j] = tanh2(z);
        }
    }

    __half2 g[2][8];
#pragma unroll
    for (int j = 0; j < 8; ++j) {
        __half2 k0 = WGETH(BASE + 40 + j * 8 + 0);
        __half2 k1 = WGETH(BASE + 40 + j * 8 + 1);
        __half2 k2 = WGETH(BASE + 40 + j * 8 + 2);
        __half2 k3 = WGETH(BASE + 40 + j * 8 + 3);
        __half2 k4 = WGETH(BASE + 40 + j * 8 + 4);
        __half2 k5 = WGETH(BASE + 40 + j * 8 + 5);
        __half2 k6 = WGETH(BASE + 40 + j * 8 + 6);
        __half2 k7 = WGETH(BASE + 40 + j * 8 + 7);
        __half2 bb = WGETH(BASE + 104 + j);
#pragma unroll
        for (int p = 0; p < 2; ++p) {
            __half2 z = __hmul2(k0, h[p][0]);
            z = __hfma2(k1, h[p][1], z);
            z = __hfma2(k2, h[p][2], z);
            z = __hfma2(k3, h[p][3], z);
            z = __hfma2(k4, h[p][4], z);
            z = __hfma2(k5, h[p][5], z);
            z = __hfma2(k6, h[p][6], z);
            z = __hfma2(k7, h[p][7], z);
            g[p][j] = tanh2(__hadd2(z, bb));
        }
    }

    {
        __half2 u0 = WGETH(BASE + 112 + 0), u1 = WGETH(BASE + 112 + 1);
        __half2 u2 = WGETH(BASE + 112 + 2), u3 = WGETH(BASE + 112 + 3);
        __half2 u4 = WGETH(BASE + 112 + 4), u5 = WGETH(BASE + 112 + 5);
        __half2 u6 = WGETH(BASE + 112 + 6), u7 = WGETH(BASE + 112 + 7);
        __half2 v0 = WGETH(BASE + 112 + 8), v1 = WGETH(BASE + 112 + 9);
        __half2 v2 = WGETH(BASE + 112 + 10), v3 = WGETH(BASE + 112 + 11);
        __half2 v4 = WGETH(BASE + 112 + 12), v5 = WGETH(BASE + 112 + 13);
        __half2 v6 = WGETH(BASE + 112 + 14), v7 = WGETH(BASE + 112 + 15);
        __half2 e0 = WGETH(BASE + 128), e1 = WGETH(BASE + 129);
#pragma unroll
        for (int p = 0; p < 2; ++p) {
            __half2 z = __hmul2(u0, g[p][0]);
            z = __hfma2(u1, g[p][1], z);
            z = __hfma2(u2, g[p][2], z);
            z = __hfma2(u3, g[p][3], z);
            z = __hfma2(u4, g[p][4], z);
            z = __hfma2(u5, g[p][5], z);
            z = __hfma2(u6, g[p][6], z);
            z = __hfma2(u7, g[p][7], z);
            o0[p] = __hadd2(z, e0);
            __half2 y = __hmul2(v0, g[p][0]);
            y = __hfma2(v1, g[p][1], y);
            y = __hfma2(v2, g[p][2], y);
            y = __hfma2(v3, g[p][3], y);
            y = __hfma2(v4, g[p][4], y);
            y = __hfma2(v5, g[p][5], y);
            y = __hfma2(v6, g[p][6], y);
            y = __hfma2(v7, g[p][7], y);
            o1[p] = __hadd2(y, e1);
        }
    }
}

// One-time gather of packed weight idx (0..259) from the 12 source arrays.
static __device__ float gather_w(int idx,
    const float* __restrict__ rr1_w, const float* __restrict__ rr1_b,
    const float* __restrict__ rr2_w, const float* __restrict__ rr2_b,
    const float* __restrict__ rr3_w, const float* __restrict__ rr3_b,
    const float* __restrict__ rc1_w, const float* __restrict__ rc1_b,
    const float* __restrict__ rc2_w, const float* __restrict__ rc2_b,
    const float* __restrict__ rc3_w, const float* __restrict__ rc3_b)
{
    if (idx < 130) {
        if (idx < 32)  return rr1_w[idx];
        if (idx < 40)  return rr1_b[idx - 32];
        if (idx < 104) return rr2_w[idx - 40];
        if (idx < 112) return rr2_b[idx - 104];
        if (idx < 128) return rr3_w[idx - 112];
        return rr3_b[idx - 128];
    }
    int k = idx - 130;
    if (k < 32)  return rc1_w[k];
    if (k < 40)  return rc1_b[k - 32];
    if (k < 104) return rc2_w[k - 40];
    if (k < 112) return rc2_b[k - 104];
    if (k < 128) return rc3_w[k - 112];
    if (k < 130) return rc3_b[k - 128];
    return 0.0f;
}

static __device__ __forceinline__ int packh2(float w) {
    __half h = __float2half_rn(w);
    __half2 d = __half2half2(h);
    return __builtin_bit_cast(int, d);
}

__global__ void __launch_bounds__(256) rollout_kernel(
    const float* __restrict__ s_star, const float* __restrict__ s0,
    const float* __restrict__ fc1_w, const float* __restrict__ fc1_b,
    const float* __restrict__ fc2_w, const float* __restrict__ fc2_b,
    const float* __restrict__ rc1_w, const float* __restrict__ rc1_b,
    const float* __restrict__ rc2_w, const float* __restrict__ rc2_b,
    const float* __restrict__ rc3_w, const float* __restrict__ rc3_b,
    const float* __restrict__ rr1_w, const float* __restrict__ rr1_b,
    const float* __restrict__ rr2_w, const float* __restrict__ rr2_b,
    const float* __restrict__ rr3_w, const float* __restrict__ rr3_b,
    float* __restrict__ out, int NQ)  // NQ = number of row-quads
{
    // Fused linear predictor (uniform; needed for the M fold below, so compute
    // before any early return): ah = A @ [s, s_star] + cb.
    float A[2][4];
    float cb[2];
#pragma unroll
    for (int r = 0; r < 2; ++r) {
#pragma unroll
        for (int c = 0; c < 4; ++c) {
            float a = 0.0f;
#pragma unroll
            for (int j = 0; j < 4; ++j)
                a = fmaf(fc2_w[r * 4 + j], fc1_w[j * 4 + c], a);
            A[r][c] = a;
        }
        float b = fc2_b[r];
#pragma unroll
        for (int j = 0; j < 4; ++j) b = fmaf(fc2_w[r * 4 + j], fc1_b[j], b);
        cb[r] = b;
    }

    // Lane-resident duplicated-f16 weights (loaded by every lane BEFORE any
    // early return so readlane never sees an uninitialized lane).
    int lane = threadIdx.x & 63;
    int wv0 = packh2(gather_w(lane,
        rr1_w, rr1_b, rr2_w, rr2_b, rr3_w, rr3_b,
        rc1_w, rc1_b, rc2_w, rc2_b, rc3_w, rc3_b));
    int wv1 = packh2(gather_w(64 + lane,
        rr1_w, rr1_b, rr2_w, rr2_b, rr3_w, rr3_b,
        rc1_w, rc1_b, rc2_w, rc2_b, rc3_w, rc3_b));
    int wv2 = packh2(gather_w(128 + lane,
        rr1_w, rr1_b, rr2_w, rr2_b, rr3_w, rr3_b,
        rc1_w, rc1_b, rc2_w, rc2_b, rc3_w, rc3_b));
    int wv3 = packh2(gather_w(192 + lane,
        rr1_w, rr1_b, rr2_w, rr2_b, rr3_w, rr3_b,
        rc1_w, rc1_b, rc2_w, rc2_b, rc3_w, rc3_b));
    int wv4 = packh2(gather_w(256 + lane,
        rr1_w, rr1_b, rr2_w, rr2_b, rr3_w, rr3_b,
        rc1_w, rc1_b, rc2_w, rc2_b, rc3_w, rc3_b));

    // wv5: folded-M coefficients. lane = pol*16 + j*2 + comp (lanes 0..31):
    //   M_{j,comp} = w1[j,comp] + w1[j,2]*A[0][comp] + w1[j,3]*A[1][comp]
    int wv5;
    {
        int pol = (lane >> 4) & 1;
        int j   = (lane >> 1) & 7;
        int cmp = lane & 1;
        const float* w1p = pol ? rc1_w : rr1_w;
        float m = fmaf(w1p[j * 4 + 2], A[0][cmp],
                  fmaf(w1p[j * 4 + 3], A[1][cmp], w1p[j * 4 + cmp]));
        wv5 = packh2(m);
    }

    int i = blockIdx.x * blockDim.x + threadIdx.x;
    if (i >= NQ) return;

    // rows 4i..4i+3
    float4 ssA = reinterpret_cast<const float4*>(s_star)[2 * i];
    float4 ssB = reinterpret_cast<const float4*>(s_star)[2 * i + 1];
    float4 svA = reinterpret_cast<const float4*>(s0)[2 * i];
    float4 svB = reinterpret_cast<const float4*>(s0)[2 * i + 1];

    float ssx[4] = {ssA.x, ssA.z, ssB.x, ssB.z};
    float ssy[4] = {ssA.y, ssA.w, ssB.y, ssB.w};
    float sx[4]  = {svA.x, svA.z, svB.x, svB.z};
    float sy[4]  = {svA.y, svA.w, svB.y, svB.w};

    float d0[4], d1[4], ahs0[4], err[4];
#pragma unroll
    for (int r = 0; r < 4; ++r) {
        d0[r] = fmaf(A[0][2], ssx[r], fmaf(A[0][3], ssy[r], cb[0]));
        d1[r] = fmaf(A[1][2], ssx[r], fmaf(A[1][3], ssy[r], cb[1]));
        ahs0[r] = (ssx[r] > 0.5f) ? -1.0f : 1.0f;
        err[r] = 0.0f;
    }

    // Per-row folded-L1 constants (f32 precompute, stored f16):
    //   c_j(row) = w1[j,2]*d0 + w1[j,3]*d1 + b1[j]
    __half2 chrr[8][2], chrc[8][2];
#pragma unroll
    for (int j = 0; j < 8; ++j) {
        float w2j = rr1_w[j * 4 + 2], w3j = rr1_w[j * 4 + 3], bj = rr1_b[j];
#pragma unroll
        for (int p = 0; p < 2; ++p) {
            float clo = fmaf(w2j, d0[2 * p],     fmaf(w3j, d1[2 * p],     bj));
            float chi = fmaf(w2j, d0[2 * p + 1], fmaf(w3j, d1[2 * p + 1], bj));
            chrr[j][p] = __floats2half2_rn(clo, chi);
        }
    }
#pragma unroll
    for (int j = 0; j < 8; ++j) {
        float w2j = rc1_w[j * 4 + 2], w3j = rc1_w[j * 4 + 3], bj = rc1_b[j];
#pragma unroll
        for (int p = 0; p < 2; ++p) {
            float clo = fmaf(w2j, d0[2 * p],     fmaf(w3j, d1[2 * p],     bj));
            float chi = fmaf(w2j, d0[2 * p + 1], fmaf(w3j, d1[2 * p + 1], bj));
            chrc[j][p] = __floats2half2_rn(clo, chi);
        }
    }

#pragma unroll 1
    for (int t = 0; t < NSTEPS; ++t) {
        float ah0[4], ah1[4];
#pragma unroll
        for (int r = 0; r < 4; ++r) {
            ah0[r] = fmaf(A[0][0], sx[r], fmaf(A[0][1], sy[r], d0[r]));
            ah1[r] = fmaf(A[1][0], sx[r], fmaf(A[1][1], sy[r], d1[r]));
        }

        // pack state: rows 2p, 2p+1 -> low/high halves
        __half2 c0[2], c1[2];
#pragma unroll
        for (int p = 0; p < 2; ++p) {
            c0[p] = __floats2half2_rn(sx[2 * p], sx[2 * p + 1]);
            c1[p] = __floats2half2_rn(sy[2 * p], sy[2 * p + 1]);
        }

        __half2 arr0h[2], arr1h[2], ar0h[2], ar1h[2];
        policy4h<0, 0>(wv0, wv1, wv2, wv3, wv4, wv5, chrr, c0, c1, arr0h, arr1h);
        policy4h<130, 16>(wv0, wv1, wv2, wv3, wv4, wv5, chrc, c0, c1, ar0h, ar1h);

#pragma unroll
        for (int p = 0; p < 2; ++p) {
            // e2 in f16: |arr - ar|^2 per row in each half
            __half2 uxh = __hsub2(arr0h[p], ar0h[p]);
            __half2 uyh = __hsub2(arr1h[p], ar1h[p]);
            __half2 n2h = __hfma2(uyh, uyh, __hmul2(uxh, uxh));
            float n2[2] = {__low2float(n2h), __high2float(n2h)};
            float a0[2] = {__low2float(ar0h[p]), __high2float(ar0h[p])};
            float a1[2] = {__low2float(ar1h[p]), __high2float(ar1h[p])};
#pragma unroll
            for (int q = 0; q < 2; ++q) {
                int r = 2 * p + q;
                sx[r] = fmaf(DT, a0[q], sx[r]);
                sy[r] = fmaf(DT, a1[q], sy[r]);

                float dx = ssx[r] - sx[r], dy = ssy[r] - sy[r];
                float n1 = fmaf(dx, dx, dy * dy);
                float vx = ahs0[r] - ah0[r];
                float n3 = fmaf(vx, vx, ah1[r] * ah1[r]);

                err[r] = err[r] + SQRTF(n1);
                err[r] = fmaf(0.1f, SQRTF(n2[q]), err[r]);
                err[r] = err[r] + SQRTF(n3);
            }
        }
    }

    float4 o;
    o.x = err[0]; o.y = err[1]; o.z = err[2]; o.w = err[3];
    reinterpret_cast<float4*>(out)[i] = o;
}

extern "C" void kernel_launch(void* const* d_in, const int* in_sizes, int n_in,
                              void* d_out, int out_size, void* d_ws, size_t ws_size,
                              hipStream_t stream) {
    const float* s_star = (const float*)d_in[0];
    const float* s0     = (const float*)d_in[1];
    const float* fc1_w  = (const float*)d_in[2];
    const float* fc1_b  = (const float*)d_in[3];
    const float* fc2_w  = (const float*)d_in[4];
    const float* fc2_b  = (const float*)d_in[5];
    const float* rc1_w  = (const float*)d_in[6];
    const float* rc1_b  = (const float*)d_in[7];
    const float* rc2_w  = (const float*)d_in[8];
    const float* rc2_b  = (const float*)d_in[9];
    const float* rc3_w  = (const float*)d_in[10];
    const float* rc3_b  = (const float*)d_in[11];
    const float* rr1_w  = (const float*)d_in[12];
    const float* rr1_b  = (const float*)d_in[13];
    const float* rr2_w  = (const float*)d_in[14];
    const float* rr2_b  = (const float*)d_in[15];
    const float* rr3_w  = (const float*)d_in[16];
    const float* rr3_b  = (const float*)d_in[17];
    float* out = (float*)d_out;

    int B = in_sizes[0] / 2;   // rows
    int NQ = B / 4;            // row-quads (B = 4194304)
    int block = 256;
    int grid = (NQ + block - 1) / block;
    rollout_kernel<<<grid, block, 0, stream>>>(
        s_star, s0, fc1_w, fc1_b, fc2_w, fc2_b,
        rc1_w, rc1_b, rc2_w, rc2_b, rc3_w, rc3_b,
        rr1_w, rr1_b, rr2_w, rr2_b, rr3_w, rr3_b,
        out, NQ);
}